// Round 1
// baseline (964.134 us; speedup 1.0000x reference)
//
#include <hip/hip_runtime.h>
#include <hip/hip_bf16.h>
#include <stdint.h>

typedef __attribute__((ext_vector_type(8))) short short8;
typedef __attribute__((ext_vector_type(4))) float floatx4;

__device__ __forceinline__ unsigned short f2bf(float f) {
    unsigned int u = __float_as_uint(f);
    u += 0x7fffu + ((u >> 16) & 1u);
    return (unsigned short)(u >> 16);
}
__device__ __forceinline__ float bf2f(unsigned short s) {
    return __uint_as_float(((unsigned int)s) << 16);
}

// ---------------------------------------------------------------------------
// Kernel 1: QKV GEMM  C[8192,3072] = x[8192,1024] @ wqkv[1024,3072]
// Epilogue scatters into qb/kb/vb [B=4,H=16,2048,64] bf16 using the faithful
// reshape quirk: for (l,d): h=flat>>17, l2=(flat&131071)>>6, kk=flat&63,
// flat = l*1024+d.
// ---------------------------------------------------------------------------
__global__ __launch_bounds__(256) void qkv_gemm(
    const float* __restrict__ A, const float* __restrict__ B,
    unsigned short* __restrict__ qb, unsigned short* __restrict__ kb,
    unsigned short* __restrict__ vb)
{
    __shared__ __align__(16) unsigned short As[128 * 40];
    __shared__ __align__(16) unsigned short Bs[128 * 40]; // transposed [n][k]
    const int tid = threadIdx.x;
    const int wave = tid >> 6, lane = tid & 63;
    const int quad = lane >> 4, lr = lane & 15;
    const int wr = wave >> 1, wc = wave & 1;
    const int bm = blockIdx.y * 128, bn = blockIdx.x * 128;

    floatx4 acc[4][4];
    #pragma unroll
    for (int i = 0; i < 4; i++)
        #pragma unroll
        for (int j = 0; j < 4; j++) acc[i][j] = (floatx4)0.0f;

    for (int k0 = 0; k0 < 1024; k0 += 32) {
        #pragma unroll
        for (int i = 0; i < 4; i++) {            // stage A: 128x32 fp32->bf16
            int idx = tid + 256 * i;
            int row = idx >> 3, c4 = (idx & 7) * 4;
            const float4 v = *(const float4*)(A + (size_t)(bm + row) * 1024 + k0 + c4);
            ushort4 o; o.x = f2bf(v.x); o.y = f2bf(v.y); o.z = f2bf(v.z); o.w = f2bf(v.w);
            *(ushort4*)&As[row * 40 + c4] = o;
        }
        #pragma unroll
        for (int i = 0; i < 4; i++) {            // stage B: 32x128 -> [n][k]
            int idx = tid + 256 * i;
            int kr = idx >> 5, c4 = (idx & 31) * 4;
            const float4 v = *(const float4*)(B + (size_t)(k0 + kr) * 3072 + bn + c4);
            Bs[(c4 + 0) * 40 + kr] = f2bf(v.x);
            Bs[(c4 + 1) * 40 + kr] = f2bf(v.y);
            Bs[(c4 + 2) * 40 + kr] = f2bf(v.z);
            Bs[(c4 + 3) * 40 + kr] = f2bf(v.w);
        }
        __syncthreads();
        short8 af[4], bfr[4];
        #pragma unroll
        for (int i = 0; i < 4; i++)
            af[i] = *(const short8*)&As[(wr * 64 + i * 16 + lr) * 40 + quad * 8];
        #pragma unroll
        for (int j = 0; j < 4; j++)
            bfr[j] = *(const short8*)&Bs[(wc * 64 + j * 16 + lr) * 40 + quad * 8];
        #pragma unroll
        for (int i = 0; i < 4; i++)
            #pragma unroll
            for (int j = 0; j < 4; j++)
                acc[i][j] = __builtin_amdgcn_mfma_f32_16x16x32_bf16(af[i], bfr[j], acc[i][j], 0, 0, 0);
        __syncthreads();
    }
    #pragma unroll
    for (int i = 0; i < 4; i++)
        #pragma unroll
        for (int j = 0; j < 4; j++)
            #pragma unroll
            for (int r = 0; r < 4; r++) {
                int row = bm + wr * 64 + i * 16 + quad * 4 + r;
                int col = bn + wc * 64 + j * 16 + lr;
                int b = row >> 11, l = row & 2047;
                int part = col >> 10, d = col & 1023;
                int flat = (l << 10) | d;
                int h = flat >> 17;
                int rem = flat & 131071;
                int l2 = rem >> 6, kk = rem & 63;
                size_t dst = ((size_t)((b * 16 + h) * 2048 + l2) << 6) + kk;
                unsigned short val = f2bf(acc[i][j][r]);
                if (part == 0) qb[dst] = val;
                else if (part == 1) kb[dst] = val;
                else vb[dst] = val;
            }
}

// ---------------------------------------------------------------------------
// Kernel 2: denominator  dr[b,l,m] = bf16( 1 / sum_h exp(q_h.k_h/8) )
// Block = one (b, 32x32 (l,m) tile); wave w owns heads 4w..4w+3; LDS reduce.
// ---------------------------------------------------------------------------
__global__ __launch_bounds__(256) void attn_denom(
    const unsigned short* __restrict__ qb, const unsigned short* __restrict__ kb,
    unsigned short* __restrict__ dr)
{
    __shared__ float Ered[4][32][32];
    const int tid = threadIdx.x;
    const int wave = tid >> 6, lane = tid & 63, quad = lane >> 4, lr = lane & 15;
    const int m0 = blockIdx.x * 32, l0 = blockIdx.y * 32, b = blockIdx.z;

    floatx4 e[2][2];
    #pragma unroll
    for (int i = 0; i < 2; i++)
        #pragma unroll
        for (int j = 0; j < 2; j++) e[i][j] = (floatx4)0.0f;

    for (int hh = 0; hh < 4; hh++) {
        const int h = wave * 4 + hh;
        const unsigned short* qbase = qb + ((size_t)(b * 16 + h) * 2048) * 64;
        const unsigned short* kbase = kb + ((size_t)(b * 16 + h) * 2048) * 64;
        short8 qf[2][2], kf[2][2];
        #pragma unroll
        for (int it = 0; it < 2; it++)
            #pragma unroll
            for (int f = 0; f < 2; f++)
                qf[it][f] = *(const short8*)(qbase + (size_t)(l0 + it * 16 + lr) * 64 + f * 32 + quad * 8);
        #pragma unroll
        for (int jt = 0; jt < 2; jt++)
            #pragma unroll
            for (int f = 0; f < 2; f++)
                kf[jt][f] = *(const short8*)(kbase + (size_t)(m0 + jt * 16 + lr) * 64 + f * 32 + quad * 8);
        #pragma unroll
        for (int it = 0; it < 2; it++)
            #pragma unroll
            for (int jt = 0; jt < 2; jt++) {
                floatx4 s = (floatx4)0.0f;
                s = __builtin_amdgcn_mfma_f32_16x16x32_bf16(qf[it][0], kf[jt][0], s, 0, 0, 0);
                s = __builtin_amdgcn_mfma_f32_16x16x32_bf16(qf[it][1], kf[jt][1], s, 0, 0, 0);
                #pragma unroll
                for (int r = 0; r < 4; r++)
                    e[it][jt][r] += __expf(s[r] * 0.125f);
            }
    }
    #pragma unroll
    for (int it = 0; it < 2; it++)
        #pragma unroll
        for (int jt = 0; jt < 2; jt++)
            #pragma unroll
            for (int r = 0; r < 4; r++)
                Ered[wave][it * 16 + quad * 4 + r][jt * 16 + lr] = e[it][jt][r];
    __syncthreads();
    #pragma unroll
    for (int r = 0; r < 4; r++) {
        int idx = r * 256 + tid;
        int ll = idx >> 5, mm = idx & 31;
        float sum = Ered[0][ll][mm] + Ered[1][ll][mm] + Ered[2][ll][mm] + Ered[3][ll][mm];
        dr[(size_t)(b * 2048 + l0 + ll) * 2048 + m0 + mm] = f2bf(1.0f / sum);
    }
}

// ---------------------------------------------------------------------------
// Kernel 3: P@V per (b,h,l-tile of 64). Recompute scores, P = exp(s/8)*dr,
// LDS round-trip P (C-layout -> A-layout), V staged transposed. Writes into
// concat layout cb[b*2048+l, h*64+k] bf16.
// ---------------------------------------------------------------------------
__global__ __launch_bounds__(256) void attn_pv(
    const unsigned short* __restrict__ qb, const unsigned short* __restrict__ kb,
    const unsigned short* __restrict__ vb, const unsigned short* __restrict__ dr,
    unsigned short* __restrict__ cb)
{
    __shared__ __align__(16) unsigned short Vt[64 * 40];      // [k-col][m]
    __shared__ __align__(16) unsigned short Pl[4][16 * 40];   // per-wave [l][m]
    const int tid = threadIdx.x;
    const int wave = tid >> 6, lane = tid & 63, quad = lane >> 4, lr = lane & 15;
    const int l0 = blockIdx.x * 64, h = blockIdx.y, b = blockIdx.z;
    const size_t head = (size_t)(b * 16 + h) * 2048;
    const unsigned short* qbase = qb + head * 64;
    const unsigned short* kbase = kb + head * 64;
    const unsigned short* vbase = vb + head * 64;
    const int lw = l0 + wave * 16;

    short8 qf0 = *(const short8*)(qbase + (size_t)(lw + lr) * 64 + quad * 8);
    short8 qf1 = *(const short8*)(qbase + (size_t)(lw + lr) * 64 + 32 + quad * 8);
    floatx4 acc[4];
    #pragma unroll
    for (int n = 0; n < 4; n++) acc[n] = (floatx4)0.0f;

    for (int m0 = 0; m0 < 2048; m0 += 32) {
        #pragma unroll
        for (int i = 0; i < 2; i++) {            // stage V[32x64] -> Vt[64][32]
            int idx = tid + 256 * i;
            int mr = idx >> 4, c4 = (idx & 15) * 4;
            ushort4 v = *(const ushort4*)(vbase + (size_t)(m0 + mr) * 64 + c4);
            Vt[(c4 + 0) * 40 + mr] = v.x;
            Vt[(c4 + 1) * 40 + mr] = v.y;
            Vt[(c4 + 2) * 40 + mr] = v.z;
            Vt[(c4 + 3) * 40 + mr] = v.w;
        }
        __syncthreads();
        #pragma unroll
        for (int jt = 0; jt < 2; jt++) {
            short8 kf0 = *(const short8*)(kbase + (size_t)(m0 + jt * 16 + lr) * 64 + quad * 8);
            short8 kf1 = *(const short8*)(kbase + (size_t)(m0 + jt * 16 + lr) * 64 + 32 + quad * 8);
            floatx4 s = (floatx4)0.0f;
            s = __builtin_amdgcn_mfma_f32_16x16x32_bf16(qf0, kf0, s, 0, 0, 0);
            s = __builtin_amdgcn_mfma_f32_16x16x32_bf16(qf1, kf1, s, 0, 0, 0);
            #pragma unroll
            for (int r = 0; r < 4; r++) {
                int l = lw + quad * 4 + r;
                int m = m0 + jt * 16 + lr;
                float rcp = bf2f(dr[(size_t)(b * 2048 + l) * 2048 + m]);
                float p = __expf(s[r] * 0.125f) * rcp;
                Pl[wave][(quad * 4 + r) * 40 + jt * 16 + lr] = f2bf(p);
            }
        }
        __syncthreads();
        short8 pa = *(const short8*)&Pl[wave][lr * 40 + quad * 8];
        #pragma unroll
        for (int n = 0; n < 4; n++) {
            short8 vf = *(const short8*)&Vt[(n * 16 + lr) * 40 + quad * 8];
            acc[n] = __builtin_amdgcn_mfma_f32_16x16x32_bf16(pa, vf, acc[n], 0, 0, 0);
        }
        __syncthreads();
    }
    #pragma unroll
    for (int n = 0; n < 4; n++)
        #pragma unroll
        for (int r = 0; r < 4; r++) {
            int l = lw + quad * 4 + r;
            int col = h * 64 + n * 16 + lr;
            cb[(size_t)(b * 2048 + l) * 1024 + col] = f2bf(acc[n][r]);
        }
}

// ---------------------------------------------------------------------------
// Kernel 4: output GEMM  out[8192,1024] = concat[8192,1024] @ wo[1024,1024]
// ---------------------------------------------------------------------------
__global__ __launch_bounds__(256) void out_gemm(
    const unsigned short* __restrict__ A, const float* __restrict__ B,
    float* __restrict__ C)
{
    __shared__ __align__(16) unsigned short As[128 * 40];
    __shared__ __align__(16) unsigned short Bs[128 * 40];
    const int tid = threadIdx.x;
    const int wave = tid >> 6, lane = tid & 63, quad = lane >> 4, lr = lane & 15;
    const int wr = wave >> 1, wc = wave & 1;
    const int bm = blockIdx.y * 128, bn = blockIdx.x * 128;

    floatx4 acc[4][4];
    #pragma unroll
    for (int i = 0; i < 4; i++)
        #pragma unroll
        for (int j = 0; j < 4; j++) acc[i][j] = (floatx4)0.0f;

    for (int k0 = 0; k0 < 1024; k0 += 32) {
        #pragma unroll
        for (int i = 0; i < 2; i++) {            // stage A (bf16 already)
            int idx = tid + 256 * i;
            int row = idx >> 2, c8 = (idx & 3) * 8;
            short8 v = *(const short8*)(A + (size_t)(bm + row) * 1024 + k0 + c8);
            *(short8*)&As[row * 40 + c8] = v;
        }
        #pragma unroll
        for (int i = 0; i < 4; i++) {            // stage B fp32->bf16 [n][k]
            int idx = tid + 256 * i;
            int kr = idx >> 5, c4 = (idx & 31) * 4;
            const float4 v = *(const float4*)(B + (size_t)(k0 + kr) * 1024 + bn + c4);
            Bs[(c4 + 0) * 40 + kr] = f2bf(v.x);
            Bs[(c4 + 1) * 40 + kr] = f2bf(v.y);
            Bs[(c4 + 2) * 40 + kr] = f2bf(v.z);
            Bs[(c4 + 3) * 40 + kr] = f2bf(v.w);
        }
        __syncthreads();
        short8 af[4], bfr[4];
        #pragma unroll
        for (int i = 0; i < 4; i++)
            af[i] = *(const short8*)&As[(wr * 64 + i * 16 + lr) * 40 + quad * 8];
        #pragma unroll
        for (int j = 0; j < 4; j++)
            bfr[j] = *(const short8*)&Bs[(wc * 64 + j * 16 + lr) * 40 + quad * 8];
        #pragma unroll
        for (int i = 0; i < 4; i++)
            #pragma unroll
            for (int j = 0; j < 4; j++)
                acc[i][j] = __builtin_amdgcn_mfma_f32_16x16x32_bf16(af[i], bfr[j], acc[i][j], 0, 0, 0);
        __syncthreads();
    }
    #pragma unroll
    for (int i = 0; i < 4; i++)
        #pragma unroll
        for (int j = 0; j < 4; j++)
            #pragma unroll
            for (int r = 0; r < 4; r++) {
                int row = bm + wr * 64 + i * 16 + quad * 4 + r;
                int col = bn + wc * 64 + j * 16 + lr;
                C[(size_t)row * 1024 + col] = acc[i][j][r];
            }
}

extern "C" void kernel_launch(void* const* d_in, const int* in_sizes, int n_in,
                              void* d_out, int out_size, void* d_ws, size_t ws_size,
                              hipStream_t stream) {
    const float* x    = (const float*)d_in[0];   // [4,2048,1024]
    const float* wqkv = (const float*)d_in[1];   // [1024,3072]
    const float* wo   = (const float*)d_in[2];   // [1024,1024]
    float* out = (float*)d_out;                  // [4,2048,1024] fp32

    unsigned short* qb = (unsigned short*)d_ws;          //  16.8 MB
    unsigned short* kb = qb + 8388608;                   //  16.8 MB
    unsigned short* vb = kb + 8388608;                   //  16.8 MB
    unsigned short* dr = vb + 8388608;                   //  33.5 MB (1/denominator, bf16)
    unsigned short* cb = dr + 16777216;                  //  16.8 MB (concat)
    // total = 100,663,296 bytes

    qkv_gemm <<<dim3(24, 64),    256, 0, stream>>>(x, wqkv, qb, kb, vb);
    attn_denom<<<dim3(64, 64, 4), 256, 0, stream>>>(qb, kb, dr);
    attn_pv  <<<dim3(32, 16, 4), 256, 0, stream>>>(qb, kb, vb, dr, cb);
    out_gemm <<<dim3(8, 64),     256, 0, stream>>>(cb, wo, out);
}